// Round 10
// baseline (139.563 us; speedup 1.0000x reference)
//
#include <hip/hip_runtime.h>
#include <hip/hip_fp16.h>
#include <math.h>

// sigAct: u0 = sigmoid(-(lam_b*conv(1-2x))/eps); 5 damped updates.
// conv = separable 17-tap Gaussian (sigma=2), f32 accumulation.
// Round-10: PAIRWISE FUSION (3 kernels: steps {0,1},{2,3},{4,5}).
// Per block (64x64 output): hpass-A reads 96x96 global halo -> sA[96][80];
// vpass-A + epilogue-A -> u_mid in LDS sU[80][80] (no global round-trip);
// hpass-B sU -> sB[80][64] (aliases sA); vpass-B + epilogue-B -> global.
// OOB sU px = 0.5 so f=1-2u=0 reproduces SAME zero-pad for step B.
// lam recomputed inline from c (xl buffer dropped). LDS 28.2KB -> 5 blk/CU.
// Lessons kept: no register-hungry prefetch (r7/r8), no grid.sync (r6),
// global-direct hpass reads (r9).

#define TILE 64
#define HW   512
#define NIMG 24
#define NPIX ((size_t)HW * HW * NIMG)

// 1D normalized Gaussian, sigma=2, 17 taps: exp(-(k-8)^2/8) / 5.0131684
__device__ __constant__ const float GWc[17] = {
    6.6916e-05f, 4.3635e-04f, 2.2159612e-03f, 8.7643070e-03f,
    2.6995958e-02f, 6.4759932e-02f, 1.2098751e-01f, 1.7603572e-01f,
    1.9947466e-01f,
    1.7603572e-01f, 1.2098751e-01f, 6.4759932e-02f, 2.6995958e-02f,
    8.7643070e-03f, 2.2159612e-03f, 4.3635e-04f, 6.6916e-05f
};

struct alignas(16) H8 { __half2 a, b, c, d; };

// sigmoid(-z) = 1/(1+exp(z)); inf->0, -inf->1.
__device__ __forceinline__ float inv1pexp(float z) {
    return __builtin_amdgcn_rcpf(1.0f + __expf(z));
}

__device__ __forceinline__ H8 pack8(const float* a) {
    H8 o;
    o.a = __floats2half2_rn(a[0], a[1]);
    o.b = __floats2half2_rn(a[2], a[3]);
    o.c = __floats2half2_rn(a[4], a[5]);
    o.d = __floats2half2_rn(a[6], a[7]);
    return o;
}

template<int MODE> // 0 = steps{0,1}(x input), 1 = mid pair, 2 = final pair (f32 out)
__global__ __launch_bounds__(256, 5) void sig_pair(
    const float* __restrict__ xg, const float* __restrict__ cgl,
    const __half* __restrict__ uin, void* __restrict__ uout)
{
    __shared__ __half sA[96 * 80];   // 15.36 KB; phase-3 reuses as sB[80][64]
    __shared__ __half sU[80 * 80];   // 12.8  KB; u_mid halo tile

    const int t    = threadIdx.x;
    const int img  = blockIdx.z;
    const int row0 = blockIdx.y * TILE;
    const int col0 = blockIdx.x * TILE;
    const size_t ibase = (size_t)img * HW * HW;

    // ===== phase 1: hpass A from GLOBAL -> sA[96][80] =====
    // unit (r,ci): sA row r <-> global row row0+r-16; out cols 8ci..8ci+8
    // (<-> global col0-8+8ci+j); reads input cols col0+8ci-16+[0,24).
#pragma unroll
    for (int i = 0; i < 4; ++i) {
        int q = t + i * 256;
        if (q < 960) {
            int r  = q / 10;
            int ci = q - r * 10;
            int gr  = row0 + r - 16;
            int gc0 = col0 + ci * 8 - 16;   // multiple of 8: chunks all-in/out
            float w[24];
#pragma unroll
            for (int j = 0; j < 24; ++j) w[j] = 0.f;
            if (gr >= 0 && gr < HW) {
                if constexpr (MODE == 0) {
                    const float* xb = xg + ibase + (size_t)gr * HW;
#pragma unroll
                    for (int j = 0; j < 6; ++j) {
                        int s = gc0 + 4 * j;
                        if (s >= 0 && s < HW) {
                            float4 v = *reinterpret_cast<const float4*>(&xb[s]);
                            w[4*j+0] = 1.f - 2.f * v.x;
                            w[4*j+1] = 1.f - 2.f * v.y;
                            w[4*j+2] = 1.f - 2.f * v.z;
                            w[4*j+3] = 1.f - 2.f * v.w;
                        }
                    }
                } else {
                    const __half* ub = uin + ibase + (size_t)gr * HW;
#pragma unroll
                    for (int j = 0; j < 3; ++j) {
                        int s = gc0 + 8 * j;
                        if (s >= 0 && s < HW) {
                            H8 v = *reinterpret_cast<const H8*>(&ub[s]);
                            float2 f0 = __half22float2(v.a);
                            float2 f1 = __half22float2(v.b);
                            float2 f2 = __half22float2(v.c);
                            float2 f3 = __half22float2(v.d);
                            w[8*j+0] = 1.f - 2.f * f0.x;
                            w[8*j+1] = 1.f - 2.f * f0.y;
                            w[8*j+2] = 1.f - 2.f * f1.x;
                            w[8*j+3] = 1.f - 2.f * f1.y;
                            w[8*j+4] = 1.f - 2.f * f2.x;
                            w[8*j+5] = 1.f - 2.f * f2.y;
                            w[8*j+6] = 1.f - 2.f * f3.x;
                            w[8*j+7] = 1.f - 2.f * f3.y;
                        }
                    }
                }
            }
            float a[8];
#pragma unroll
            for (int j = 0; j < 8; ++j) {
                float acc = 0.f;
#pragma unroll
                for (int k = 0; k < 17; ++k) acc += GWc[k] * w[j + k];
                a[j] = acc;
            }
            *reinterpret_cast<H8*>(&sA[r * 80 + ci * 8]) = pack8(a);
        }
    }
    __syncthreads();

    // ===== phase 2: vpass A + epilogue A -> sU[80][80] =====
    // unit (r,ci): sU row r <-> global row row0+r-8; cols col0-8+8ci+[0,8)
#pragma unroll
    for (int i = 0; i < 4; ++i) {
        int q = t + i * 256;
        if (q < 800) {
            int r  = q / 10;
            int ci = q - r * 10;
            float a0=0.f,a1=0.f,a2=0.f,a3=0.f,a4=0.f,a5=0.f,a6=0.f,a7=0.f;
#pragma unroll
            for (int k = 0; k < 17; ++k) {
                H8 v = *reinterpret_cast<const H8*>(&sA[(r + k) * 80 + ci * 8]);
                float g = GWc[k];
                float2 f0 = __half22float2(v.a);
                float2 f1 = __half22float2(v.b);
                float2 f2 = __half22float2(v.c);
                float2 f3 = __half22float2(v.d);
                a0 += g * f0.x; a1 += g * f0.y; a2 += g * f1.x; a3 += g * f1.y;
                a4 += g * f2.x; a5 += g * f2.y; a6 += g * f3.x; a7 += g * f3.y;
            }
            float acc[8] = { a0,a1,a2,a3,a4,a5,a6,a7 };
            int gr  = row0 + r - 8;
            int gc0 = col0 + ci * 8 - 8;    // multiple of 8
            float res[8];
            if (gr >= 0 && gr < HW && gc0 >= 0 && gc0 < HW) {
                size_t gb = ibase + (size_t)gr * HW + gc0;
                float4 c0 = *reinterpret_cast<const float4*>(&cgl[gb]);
                float4 c1 = *reinterpret_cast<const float4*>(&cgl[gb + 4]);
                float cv[8] = { c0.x,c0.y,c0.z,c0.w, c1.x,c1.y,c1.z,c1.w };
                if constexpr (MODE == 0) {
#pragma unroll
                    for (int j = 0; j < 8; ++j) {
                        float lam = 100.f * inv1pexp(-10.f * cv[j]);
                        res[j] = inv1pexp(lam * acc[j] * 0.1f);
                    }
                } else {
                    H8 u8 = *reinterpret_cast<const H8*>(&uin[gb]);
                    float2 u0 = __half22float2(u8.a), u1 = __half22float2(u8.b);
                    float2 u2 = __half22float2(u8.c), u3 = __half22float2(u8.d);
                    float up[8] = { u0.x,u0.y,u1.x,u1.y,u2.x,u2.y,u3.x,u3.y };
                    float4 x0 = *reinterpret_cast<const float4*>(&xg[gb]);
                    float4 x1 = *reinterpret_cast<const float4*>(&xg[gb + 4]);
                    float xv[8] = { x0.x,x0.y,x0.z,x0.w, x1.x,x1.y,x1.z,x1.w };
#pragma unroll
                    for (int j = 0; j < 8; ++j) {
                        float lam = 100.f * inv1pexp(-10.f * cv[j]);
                        float tt  = (up[j] - xv[j]) * 10.f + lam * acc[j];
                        float uu  = inv1pexp(tt * 0.1f);
                        res[j] = 0.5f * (up[j] + uu);
                    }
                }
            } else {
#pragma unroll
                for (int j = 0; j < 8; ++j) res[j] = 0.5f;  // OOB: f=1-2u=0 pad
            }
            *reinterpret_cast<H8*>(&sU[r * 80 + ci * 8]) = pack8(res);
        }
    }
    __syncthreads();

    // ===== phase 3: hpass B from sU -> sB[80][64] (aliases sA) =====
    __half* sB = sA;
#pragma unroll
    for (int i = 0; i < 3; ++i) {
        int q = t + i * 256;
        if (q < 640) {
            int r  = q >> 3;
            int ci = q & 7;
            float w[24];
#pragma unroll
            for (int jj = 0; jj < 3; ++jj) {
                H8 v = *reinterpret_cast<const H8*>(&sU[r * 80 + ci * 8 + jj * 8]);
                float2 f0 = __half22float2(v.a);
                float2 f1 = __half22float2(v.b);
                float2 f2 = __half22float2(v.c);
                float2 f3 = __half22float2(v.d);
                w[8*jj+0] = 1.f - 2.f * f0.x;
                w[8*jj+1] = 1.f - 2.f * f0.y;
                w[8*jj+2] = 1.f - 2.f * f1.x;
                w[8*jj+3] = 1.f - 2.f * f1.y;
                w[8*jj+4] = 1.f - 2.f * f2.x;
                w[8*jj+5] = 1.f - 2.f * f2.y;
                w[8*jj+6] = 1.f - 2.f * f3.x;
                w[8*jj+7] = 1.f - 2.f * f3.y;
            }
            float a[8];
#pragma unroll
            for (int j = 0; j < 8; ++j) {
                float acc = 0.f;
#pragma unroll
                for (int k = 0; k < 17; ++k) acc += GWc[k] * w[j + k];
                a[j] = acc;
            }
            *reinterpret_cast<H8*>(&sB[r * 64 + ci * 8]) = pack8(a);
        }
    }
    __syncthreads();

    // ===== phase 4: vpass B + epilogue B -> global =====
    const int cc = t & 63;
    const int rg = t >> 6;
    const __half* sBr = sA;
    float win[32];
#pragma unroll
    for (int j = 0; j < 32; ++j)
        win[j] = __half2float(sBr[(rg * 16 + j) * 64 + cc]);

#pragma unroll
    for (int m = 0; m < 16; ++m) {
        float acc = 0.f;
#pragma unroll
        for (int k = 0; k < 17; ++k) acc += GWc[k] * win[m + k];

        size_t gidx = ibase + (size_t)(row0 + rg * 16 + m) * HW + (col0 + cc);
        float uprev = __half2float(sU[(rg * 16 + m + 8) * 80 + (cc + 8)]);
        float lam = 100.f * inv1pexp(-10.f * cgl[gidx]);   // 100*sigmoid(10c)
        float xv  = xg[gidx];
        float tt  = (uprev - xv) * 10.f + lam * acc;       // (u-x)/tau + lam*v
        float uu  = inv1pexp(tt * 0.1f);                   // sigmoid(-tt/eps)
        float res = 0.5f * (uprev + uu);                   // alpha = 0.5
        if constexpr (MODE == 2) ((float*)uout)[gidx] = res;
        else                     ((__half*)uout)[gidx] = __float2half(res);
    }
}

extern "C" void kernel_launch(void* const* d_in, const int* in_sizes, int n_in,
                              void* d_out, int out_size, void* d_ws, size_t ws_size,
                              hipStream_t stream) {
    const float* x = (const float*)d_in[0];
    const float* c = (const float*)d_in[1];

    __half* u2 = (__half*)d_ws;          // 12.6 MB
    __half* u4 = u2 + NPIX;              // 12.6 MB

    dim3 grid(HW / TILE, HW / TILE, NIMG);   // 8 x 8 x 24
    dim3 block(256);
    sig_pair<0><<<grid, block, 0, stream>>>(x, c, nullptr, u2);  // steps 0,1
    sig_pair<1><<<grid, block, 0, stream>>>(x, c, u2, u4);       // steps 2,3
    sig_pair<2><<<grid, block, 0, stream>>>(x, c, u4, d_out);    // steps 4,5
}

// Round 11
// 116.437 us; speedup vs baseline: 1.1986x; 1.1986x over previous
//
#include <hip/hip_runtime.h>
#include <hip/hip_fp16.h>
#include <math.h>

// sigAct: u0 = sigmoid(-(lam_b*conv(1-2x))/eps); 5 damped updates.
// conv = separable 17-tap Gaussian (sigma=2), f32 accumulation.
// Round-11 = round-9 structure + two levers:
//  (1) 32x64 tile, grid 3072, __launch_bounds__(256,8) -> 8 blocks/CU
//      = 32 waves/CU (100% occupancy; r9 was 75%). sTmp only 6 KB.
//  (2) transform folding: since sum(g)=1, conv(1-2u) == 1 - 2*blur(u)
//      when OOB is padded 0.5 (exactly reproduces SAME zero-pad of 1-2u).
//      hpass is a plain blur; epilogue applies f = 1-2v. Saves ~60 VALU/thr.
// Kept: global-direct hpass reads (r9), xl=(x,lam) half2 (r5), no
// register-hungry prefetch (r7/r8), no grid.sync (r6), no pair fusion (r10).

#define TR   32              // tile rows (output)
#define TC   64              // tile cols (output)
#define HR   48              // TR + 16 (hpass halo rows)
#define RAD  8
#define HW   512
#define NIMG 24
#define NPIX ((size_t)HW * HW * NIMG)

// 1D normalized Gaussian, sigma=2, 17 taps: exp(-(k-8)^2/8) / 5.0131684
__device__ __constant__ const float GWc[17] = {
    6.6916e-05f, 4.3635e-04f, 2.2159612e-03f, 8.7643070e-03f,
    2.6995958e-02f, 6.4759932e-02f, 1.2098751e-01f, 1.7603572e-01f,
    1.9947466e-01f,
    1.7603572e-01f, 1.2098751e-01f, 6.4759932e-02f, 2.6995958e-02f,
    8.7643070e-03f, 2.2159612e-03f, 4.3635e-04f, 6.6916e-05f
};

struct alignas(16) H8 { __half2 a, b, c, d; };

// sigmoid(-z) = 1/(1+exp(z)); inf->0, -inf->1.
__device__ __forceinline__ float inv1pexp(float z) {
    return __builtin_amdgcn_rcpf(1.0f + __expf(z));
}

template<int MODE> // 0=INIT 1=MID 2=FINAL
__global__ __launch_bounds__(256, 8) void sig_step(
    const float* __restrict__ xg, const float* __restrict__ cgl,
    const __half* __restrict__ uin, __half2* __restrict__ xl,
    void* __restrict__ uout)
{
    __shared__ __half sTmp[HR * TC];   // h-blur output, 6 KB (only LDS)

    const int t    = threadIdx.x;
    const int img  = blockIdx.z;
    const int row0 = blockIdx.y * TR;
    const int col0 = blockIdx.x * TC;
    const size_t ibase = (size_t)img * HW * HW;

    // ===== h-blur: 384 units = (halo row r in [0,48), col-group ci in [0,8)) =====
    // unit reads input cols col0+8ci-8 .. +16 from GLOBAL (pad 0.5),
    // writes 8 half blur values to sTmp[r][8ci..8ci+8).
#pragma unroll
    for (int i = 0; i < 2; ++i) {
        int q = t + i * 256;
        if (q < HR * 8) {
            int r  = q >> 3;               // halo row 0..47
            int ci = q & 7;                // col group 0..7
            int gr = row0 + r - RAD;
            float w[24];
#pragma unroll
            for (int j = 0; j < 24; ++j) w[j] = 0.5f;   // 0.5-pad == SAME pad
            if (gr >= 0 && gr < HW) {
                int gc0 = col0 + ci * 8 - RAD;
                if constexpr (MODE == 0) {
                    const float* xb = xg + ibase + (size_t)gr * HW;
#pragma unroll
                    for (int j = 0; j < 6; ++j) {
                        int s = gc0 + 4 * j;
                        if (s >= 0 && s < HW) {
                            float4 v = *reinterpret_cast<const float4*>(&xb[s]);
                            w[4*j+0] = v.x; w[4*j+1] = v.y;
                            w[4*j+2] = v.z; w[4*j+3] = v.w;
                        }
                    }
                } else {
                    const __half* ub = uin + ibase + (size_t)gr * HW;
#pragma unroll
                    for (int j = 0; j < 3; ++j) {
                        int s = gc0 + 8 * j;
                        if (s >= 0 && s < HW) {
                            H8 v = *reinterpret_cast<const H8*>(&ub[s]);
                            float2 f0 = __half22float2(v.a);
                            float2 f1 = __half22float2(v.b);
                            float2 f2 = __half22float2(v.c);
                            float2 f3 = __half22float2(v.d);
                            w[8*j+0] = f0.x; w[8*j+1] = f0.y;
                            w[8*j+2] = f1.x; w[8*j+3] = f1.y;
                            w[8*j+4] = f2.x; w[8*j+5] = f2.y;
                            w[8*j+6] = f3.x; w[8*j+7] = f3.y;
                        }
                    }
                }
            }
            float a[8];
#pragma unroll
            for (int j = 0; j < 8; ++j) {
                float acc = 0.f;
#pragma unroll
                for (int k = 0; k < 17; ++k) acc += GWc[k] * w[j + k];
                a[j] = acc;
            }
            H8 o;
            o.a = __floats2half2_rn(a[0], a[1]);
            o.b = __floats2half2_rn(a[2], a[3]);
            o.c = __floats2half2_rn(a[4], a[5]);
            o.d = __floats2half2_rn(a[6], a[7]);
            *reinterpret_cast<H8*>(&sTmp[r * TC + ci * 8]) = o;
        }
    }
    __syncthreads();

    // ===== v-blur (1 col x 8 rows/thread) + pointwise epilogue =====
    const int cc = t & 63;
    const int rg = t >> 6;                 // 4 row groups x 8 rows
    const size_t pbase = ibase + (size_t)(row0 + rg * 8) * HW + (col0 + cc);

    float win[24];
#pragma unroll
    for (int j = 0; j < 24; ++j)
        win[j] = __half2float(sTmp[(rg * 8 + j) * TC + cc]);

#pragma unroll
    for (int m = 0; m < 8; ++m) {
        float v = 0.f;
#pragma unroll
        for (int k = 0; k < 17; ++k) v += GWc[k] * win[m + k];
        float f = 1.f - 2.f * v;           // == conv(1-2u), SAME zero-pad

        size_t gidx = pbase + (size_t)m * HW;
        if constexpr (MODE == 0) {
            float xv  = xg[gidx];
            float lam = 100.f * inv1pexp(-10.f * cgl[gidx]);  // 100*sig(10c)
            xl[gidx] = __floats2half2_rn(xv, lam);
            ((__half*)uout)[gidx] = __float2half(inv1pexp(lam * f * 0.1f));
        } else {
            float2 p = __half22float2(xl[gidx]);              // (x, lam)
            float uprev = __half2float(uin[gidx]);            // L1/L2-hot
            float tt = (uprev - p.x) * 10.f + p.y * f;        // (u-x)/tau+lam*v
            float uu = inv1pexp(tt * 0.1f);                   // sigmoid(-tt/eps)
            float res = 0.5f * (uprev + uu);                  // alpha = 0.5
            if constexpr (MODE == 2) ((float*)uout)[gidx] = res;
            else                     ((__half*)uout)[gidx] = __float2half(res);
        }
    }
}

extern "C" void kernel_launch(void* const* d_in, const int* in_sizes, int n_in,
                              void* d_out, int out_size, void* d_ws, size_t ws_size,
                              hipStream_t stream) {
    const float* x = (const float*)d_in[0];
    const float* c = (const float*)d_in[1];

    __half* u0 = (__half*)d_ws;          // NPIX halfs = 12.6 MB
    __half* u1 = u0 + NPIX;              // 12.6 MB
    __half2* xl = (ws_size >= NPIX * 8)
        ? (__half2*)((char*)d_ws + NPIX * 4)
        : (__half2*)d_out;               // safe: per-pixel read-before-write

    dim3 grid(HW / TC, HW / TR, NIMG);   // 8 x 16 x 24 = 3072 blocks
    dim3 block(256);
    sig_step<0><<<grid, block, 0, stream>>>(x, c, nullptr, xl, u0);
    sig_step<1><<<grid, block, 0, stream>>>(x, c, u0, xl, u1);
    sig_step<1><<<grid, block, 0, stream>>>(x, c, u1, xl, u0);
    sig_step<1><<<grid, block, 0, stream>>>(x, c, u0, xl, u1);
    sig_step<1><<<grid, block, 0, stream>>>(x, c, u1, xl, u0);
    sig_step<2><<<grid, block, 0, stream>>>(x, c, u0, xl, d_out);
}

// Round 12
// 102.220 us; speedup vs baseline: 1.3653x; 1.1391x over previous
//
#include <hip/hip_runtime.h>
#include <hip/hip_fp16.h>
#include <math.h>

// sigAct: u0 = sigmoid(-(lam_b*conv(1-2x))/eps); 5 damped updates.
// conv = separable 17-tap Gaussian (sigma=2); folding: conv(1-2u) = 1-2*blur(u)
// with 0.5-padding (== SAME zero-pad of 1-2u), blur in two LDS passes.
// Round-12: h-blur via v_dot2_f32_f16 (2 fp16 mul + f32 acc per inst).
// fp16 u consumed as half2 pairs directly: 8 dot2 + 1 fma per output vs
// 24 cvt + 17 fma. 192 wave-uniform units x 16 cols. vblur/epilogue = r11.
// Lessons: occupancy-insensitive (r9==r11), no reg-hungry prefetch (r7/r8),
// no grid.sync (r6), no pair fusion (r10) -> attack VALU inst count.

#define TR   32
#define TC   64
#define HR   48              // TR + 16
#define RAD  8
#define HW   512
#define NIMG 24
#define NPIX ((size_t)HW * HW * NIMG)

typedef _Float16 h2 __attribute__((ext_vector_type(2)));
typedef unsigned int uint;

// 1D normalized Gaussian, sigma=2, 17 taps: exp(-(k-8)^2/8) / 5.0131684
#define G0  6.6916e-05f
#define G1  4.3635e-04f
#define G2  2.2159612e-03f
#define G3  8.7643070e-03f
#define G4  2.6995958e-02f
#define G5  6.4759932e-02f
#define G6  1.2098751e-01f
#define G7  1.7603572e-01f
#define G8  1.9947466e-01f
__device__ __constant__ const float GWc[17] = {
    G0,G1,G2,G3,G4,G5,G6,G7,G8,G7,G6,G5,G4,G3,G2,G1,G0
};

// sigmoid(-z) = 1/(1+exp(z)); inf->0, -inf->1.
__device__ __forceinline__ float inv1pexp(float z) {
    return __builtin_amdgcn_rcpf(1.0f + __expf(z));
}

__device__ __forceinline__ float fdot2f(uint a, h2 b, float c) {
#if __has_builtin(__builtin_amdgcn_fdot2)
    return __builtin_amdgcn_fdot2(__builtin_bit_cast(h2, a), b, c, false);
#else
    h2 av = __builtin_bit_cast(h2, a);
    return (float)av.x * (float)b.x + (float)av.y * (float)b.y + c;
#endif
}
__device__ __forceinline__ float lo16f(uint v) {
    __half h = __ushort_as_half((unsigned short)(v & 0xffffu));
    return __half2float(h);
}
__device__ __forceinline__ float hi16f(uint v) {
    __half h = __ushort_as_half((unsigned short)(v >> 16));
    return __half2float(h);
}
__device__ __forceinline__ h2 gpair(int i) {
    // (G[2i], G[2i+1]) as fp16 pair, compile-time folded
    const float G[16] = { G0,G1,G2,G3,G4,G5,G6,G7,G8,G7,G6,G5,G4,G3,G2,G1 };
    h2 r; r.x = (_Float16)G[2*i]; r.y = (_Float16)G[2*i+1]; return r;
}

template<int MODE> // 0=INIT 1=MID 2=FINAL
__global__ __launch_bounds__(256, 6) void sig_step(
    const float* __restrict__ xg, const float* __restrict__ cgl,
    const __half* __restrict__ uin, __half2* __restrict__ xl,
    void* __restrict__ uout)
{
    __shared__ __half sTmp[HR * TC];   // h-blur output, 6 KB

    const int t    = threadIdx.x;
    const int img  = blockIdx.z;
    const int row0 = blockIdx.y * TR;
    const int col0 = blockIdx.x * TC;
    const size_t ibase = (size_t)img * HW * HW;

    // ===== h-blur: 192 units (48 halo rows x 4 groups of 16 cols) =====
    if (t < 192) {
        const int r   = t >> 2;             // 0..47
        const int ci2 = t & 3;              // 0..3
        const int gr  = row0 + r - RAD;
        const int gc0 = col0 + ci2 * 16 - RAD;   // window cols [gc0, gc0+32)

        uint wv[16];                        // (w[2i], w[2i+1]) half2 pairs
#pragma unroll
        for (int i = 0; i < 16; ++i) wv[i] = 0x38003800u;  // (0.5, 0.5) pad
        if (gr >= 0 && gr < HW) {
            if constexpr (MODE == 0) {
#pragma unroll
                for (int k = 0; k < 4; ++k) {
                    int s = gc0 + 8 * k;
                    if (s >= 0 && s < HW) {
                        const float* xb = xg + ibase + (size_t)gr * HW + s;
                        float4 va = *reinterpret_cast<const float4*>(xb);
                        float4 vb = *reinterpret_cast<const float4*>(xb + 4);
                        wv[4*k+0] = __builtin_bit_cast(uint, __floats2half2_rn(va.x, va.y));
                        wv[4*k+1] = __builtin_bit_cast(uint, __floats2half2_rn(va.z, va.w));
                        wv[4*k+2] = __builtin_bit_cast(uint, __floats2half2_rn(vb.x, vb.y));
                        wv[4*k+3] = __builtin_bit_cast(uint, __floats2half2_rn(vb.z, vb.w));
                    }
                }
            } else {
#pragma unroll
                for (int k = 0; k < 4; ++k) {
                    int s = gc0 + 8 * k;
                    if (s >= 0 && s < HW) {
                        uint4 v = *reinterpret_cast<const uint4*>(
                                      uin + ibase + (size_t)gr * HW + s);
                        wv[4*k+0] = v.x; wv[4*k+1] = v.y;
                        wv[4*k+2] = v.z; wv[4*k+3] = v.w;
                    }
                }
            }
        }
        // odd-aligned pairs: wo[i] = (w[2i+1], w[2i+2])
        uint wo[15];
#pragma unroll
        for (int i = 0; i < 15; ++i)
            wo[i] = __builtin_amdgcn_alignbit(wv[i + 1], wv[i], 16);

        // 16 outputs j: a[j] = sum_{i<8} dot2(w[j+2i..], g[2i..]) + G0*w[j+16]
        uint ow[8];
#pragma unroll
        for (int jp = 0; jp < 8; ++jp) {
            float a0 = 0.f, a1 = 0.f;
#pragma unroll
            for (int i = 0; i < 8; ++i) {
                h2 g = gpair(i);
                a0 = fdot2f(wv[jp + i], g, a0);   // j = 2*jp
                a1 = fdot2f(wo[jp + i], g, a1);   // j = 2*jp+1
            }
            a0 = fmaf(G0, lo16f(wv[jp + 8]), a0);
            a1 = fmaf(G0, hi16f(wv[jp + 8]), a1);
            ow[jp] = __builtin_bit_cast(uint, __floats2half2_rn(a0, a1));
        }
        uint4* orow = reinterpret_cast<uint4*>(&sTmp[r * TC + ci2 * 16]);
        orow[0] = make_uint4(ow[0], ow[1], ow[2], ow[3]);
        orow[1] = make_uint4(ow[4], ow[5], ow[6], ow[7]);
    }
    __syncthreads();

    // ===== v-blur (1 col x 8 rows/thread) + pointwise epilogue =====
    const int cc = t & 63;
    const int rg = t >> 6;                 // 4 row groups x 8 rows
    const size_t pbase = ibase + (size_t)(row0 + rg * 8) * HW + (col0 + cc);

    float win[24];
#pragma unroll
    for (int j = 0; j < 24; ++j)
        win[j] = __half2float(sTmp[(rg * 8 + j) * TC + cc]);

#pragma unroll
    for (int m = 0; m < 8; ++m) {
        float v = 0.f;
#pragma unroll
        for (int k = 0; k < 17; ++k) v += GWc[k] * win[m + k];
        float f = 1.f - 2.f * v;           // == conv(1-2u), SAME zero-pad

        size_t gidx = pbase + (size_t)m * HW;
        if constexpr (MODE == 0) {
            float xv  = xg[gidx];
            float lam = 100.f * inv1pexp(-10.f * cgl[gidx]);  // 100*sig(10c)
            xl[gidx] = __floats2half2_rn(xv, lam);
            ((__half*)uout)[gidx] = __float2half(inv1pexp(lam * f * 0.1f));
        } else {
            float2 p = __half22float2(xl[gidx]);              // (x, lam)
            float uprev = __half2float(uin[gidx]);            // L1/L2-hot
            float tt = (uprev - p.x) * 10.f + p.y * f;        // (u-x)/tau+lam*v
            float uu = inv1pexp(tt * 0.1f);                   // sigmoid(-tt/eps)
            float res = 0.5f * (uprev + uu);                  // alpha = 0.5
            if constexpr (MODE == 2) ((float*)uout)[gidx] = res;
            else                     ((__half*)uout)[gidx] = __float2half(res);
        }
    }
}

extern "C" void kernel_launch(void* const* d_in, const int* in_sizes, int n_in,
                              void* d_out, int out_size, void* d_ws, size_t ws_size,
                              hipStream_t stream) {
    const float* x = (const float*)d_in[0];
    const float* c = (const float*)d_in[1];

    __half* u0 = (__half*)d_ws;          // NPIX halfs = 12.6 MB
    __half* u1 = u0 + NPIX;              // 12.6 MB
    __half2* xl = (ws_size >= NPIX * 8)
        ? (__half2*)((char*)d_ws + NPIX * 4)
        : (__half2*)d_out;               // safe: per-pixel read-before-write

    dim3 grid(HW / TC, HW / TR, NIMG);   // 8 x 16 x 24 = 3072 blocks
    dim3 block(256);
    sig_step<0><<<grid, block, 0, stream>>>(x, c, nullptr, xl, u0);
    sig_step<1><<<grid, block, 0, stream>>>(x, c, u0, xl, u1);
    sig_step<1><<<grid, block, 0, stream>>>(x, c, u1, xl, u0);
    sig_step<1><<<grid, block, 0, stream>>>(x, c, u0, xl, u1);
    sig_step<1><<<grid, block, 0, stream>>>(x, c, u1, xl, u0);
    sig_step<2><<<grid, block, 0, stream>>>(x, c, u0, xl, d_out);
}

// Round 14
// 99.980 us; speedup vs baseline: 1.3959x; 1.0224x over previous
//
#include <hip/hip_runtime.h>
#include <hip/hip_fp16.h>
#include <math.h>

// sigAct: u0 = sigmoid(-(lam_b*conv(1-2x))/eps); 5 damped updates.
// conv = separable 17-tap Gaussian (sigma=2); folding: conv(1-2u) = 1-2*blur(u)
// with 0.5-padding (== SAME zero-pad of 1-2u).
// Round-14 = round-13 with the halo-row off-by-8 fixed (gr = row0+2rp+rr-RAD;
// r13 had -16, shifting the v-window by 8 rows -> O(1) error).
// dot2 BOTH passes: h-blur units = 2 rows x 8 cols, output ROW-PAIRED
// sP[24][64] uint = half2(row 2p, row 2p+1); v-blur = 12 ds_read_b32 +
// alignbit + 8x(8 dot2 + tail fma), f32 accumulation everywhere.
// Lessons: VALU-inst-count bound (r12 -14us); occupancy-insensitive (r11);
// no reg-hungry prefetch (r7/r8); no grid.sync (r6); no pair fusion (r10).

#define TR   32
#define TC   64
#define RAD  8
#define HW   512
#define NIMG 24
#define NPIX ((size_t)HW * HW * NIMG)

typedef _Float16 h2 __attribute__((ext_vector_type(2)));
typedef unsigned int uint;

// 1D normalized Gaussian, sigma=2, 17 taps: exp(-(k-8)^2/8) / 5.0131684
#define G0  6.6916e-05f
#define G1  4.3635e-04f
#define G2  2.2159612e-03f
#define G3  8.7643070e-03f
#define G4  2.6995958e-02f
#define G5  6.4759932e-02f
#define G6  1.2098751e-01f
#define G7  1.7603572e-01f
#define G8  1.9947466e-01f

// sigmoid(-z) = 1/(1+exp(z)); inf->0, -inf->1.
__device__ __forceinline__ float inv1pexp(float z) {
    return __builtin_amdgcn_rcpf(1.0f + __expf(z));
}

__device__ __forceinline__ float fdot2f(uint a, h2 b, float c) {
#if __has_builtin(__builtin_amdgcn_fdot2)
    return __builtin_amdgcn_fdot2(__builtin_bit_cast(h2, a), b, c, false);
#else
    h2 av = __builtin_bit_cast(h2, a);
    return (float)av.x * (float)b.x + (float)av.y * (float)b.y + c;
#endif
}
__device__ __forceinline__ float lo16f(uint v) {
    return __half2float(__ushort_as_half((unsigned short)(v & 0xffffu)));
}
__device__ __forceinline__ float hi16f(uint v) {
    return __half2float(__ushort_as_half((unsigned short)(v >> 16)));
}
__device__ __forceinline__ h2 gpair(int i) {
    // (G[2i], G[2i+1]) fp16, compile-time folded (i = 0..7, taps 0..15)
    const float G[16] = { G0,G1,G2,G3,G4,G5,G6,G7,G8,G7,G6,G5,G4,G3,G2,G1 };
    h2 r; r.x = (_Float16)G[2*i]; r.y = (_Float16)G[2*i+1]; return r;
}
__device__ __forceinline__ uint packh2(float lo, float hi) {
    return __builtin_bit_cast(uint, __floats2half2_rn(lo, hi));
}

// 17-tap dot over a 24-half window (12 even-pairs wv + 11 odd-pairs wo):
// outputs at window offsets 2jp (even) and 2jp+1 (odd).
__device__ __forceinline__ void dot17(const uint* wv, const uint* wo,
                                      int jp, float& aE, float& aO) {
    float a0 = 0.f, a1 = 0.f;
#pragma unroll
    for (int i = 0; i < 8; ++i) {
        h2 g = gpair(i);
        a0 = fdot2f(wv[jp + i], g, a0);
        a1 = fdot2f(wo[jp + i], g, a1);
    }
    aE = fmaf(G0, lo16f(wv[jp + 8]), a0);
    aO = fmaf(G0, hi16f(wv[jp + 8]), a1);
}

template<int MODE> // 0=INIT 1=MID 2=FINAL
__global__ __launch_bounds__(256, 6) void sig_step(
    const float* __restrict__ xg, const float* __restrict__ cgl,
    const __half* __restrict__ uin, __half2* __restrict__ xl,
    void* __restrict__ uout)
{
    __shared__ uint sP[24 * 64];   // row-paired h-blur output, 6 KB

    const int t    = threadIdx.x;
    const int img  = blockIdx.z;
    const int row0 = blockIdx.y * TR;
    const int col0 = blockIdx.x * TC;
    const size_t ibase = (size_t)img * HW * HW;

    // ===== h-blur: 192 units = (pair-row rp in [0,24), 8-col group ci) =====
    if (t < 192) {
        const int rp  = t >> 3;               // 0..23
        const int ci  = t & 7;                // 0..7
        const int gc0 = col0 + ci * 8 - RAD;  // window cols [gc0, gc0+24), mult 8
        float aE[2][4], aO[2][4];
#pragma unroll
        for (int rr = 0; rr < 2; ++rr) {
            const int gr = row0 + 2 * rp + rr - RAD;  // halo row 2rp+rr in [0,48)
            uint wv[12];
#pragma unroll
            for (int i = 0; i < 12; ++i) wv[i] = 0x38003800u;  // (0.5,0.5) pad
            if (gr >= 0 && gr < HW) {
                if constexpr (MODE == 0) {
                    const float* xb = xg + ibase + (size_t)gr * HW;
#pragma unroll
                    for (int k = 0; k < 6; ++k) {
                        int s = gc0 + 4 * k;
                        if (s >= 0 && s < HW) {
                            float4 v = *reinterpret_cast<const float4*>(&xb[s]);
                            wv[2*k]   = packh2(v.x, v.y);
                            wv[2*k+1] = packh2(v.z, v.w);
                        }
                    }
                } else {
                    const __half* ub = uin + ibase + (size_t)gr * HW;
#pragma unroll
                    for (int k = 0; k < 3; ++k) {
                        int s = gc0 + 8 * k;
                        if (s >= 0 && s < HW) {
                            uint4 v = *reinterpret_cast<const uint4*>(&ub[s]);
                            wv[4*k+0] = v.x; wv[4*k+1] = v.y;
                            wv[4*k+2] = v.z; wv[4*k+3] = v.w;
                        }
                    }
                }
            }
            uint wo[11];
#pragma unroll
            for (int i = 0; i < 11; ++i)
                wo[i] = __builtin_amdgcn_alignbit(wv[i + 1], wv[i], 16);
#pragma unroll
            for (int jp = 0; jp < 4; ++jp)
                dot17(wv, wo, jp, aE[rr][jp], aO[rr][jp]);
        }
        // pack row-pairs: sP[rp][8ci+j] = (row 2rp, row 2rp+1)
        uint4* orow = reinterpret_cast<uint4*>(&sP[rp * 64 + ci * 8]);
        orow[0] = make_uint4(packh2(aE[0][0], aE[1][0]), packh2(aO[0][0], aO[1][0]),
                             packh2(aE[0][1], aE[1][1]), packh2(aO[0][1], aO[1][1]));
        orow[1] = make_uint4(packh2(aE[0][2], aE[1][2]), packh2(aO[0][2], aO[1][2]),
                             packh2(aE[0][3], aE[1][3]), packh2(aO[0][3], aO[1][3]));
    }
    __syncthreads();

    // ===== v-blur via dot2 (1 col x 8 rows/thread) + pointwise epilogue =====
    const int cc = t & 63;
    const int rg = t >> 6;                 // 4 row groups x 8 rows
    const size_t pbase = ibase + (size_t)(row0 + rg * 8) * HW + (col0 + cc);

    uint p[12];                            // pairs rg*4 .. rg*4+11, column cc
#pragma unroll
    for (int j = 0; j < 12; ++j)
        p[j] = sP[(rg * 4 + j) * 64 + cc];
    uint po[11];
#pragma unroll
    for (int j = 0; j < 11; ++j)
        po[j] = __builtin_amdgcn_alignbit(p[j + 1], p[j], 16);

#pragma unroll
    for (int jp = 0; jp < 4; ++jp) {
        float vE, vO;
        dot17(p, po, jp, vE, vO);
#pragma unroll
        for (int h = 0; h < 2; ++h) {
            int m = 2 * jp + h;
            float v = h ? vO : vE;
            float f = 1.f - 2.f * v;       // == conv(1-2u), SAME zero-pad

            size_t gidx = pbase + (size_t)m * HW;
            if constexpr (MODE == 0) {
                float xv  = xg[gidx];
                float lam = 100.f * inv1pexp(-10.f * cgl[gidx]); // 100*sig(10c)
                xl[gidx] = __floats2half2_rn(xv, lam);
                ((__half*)uout)[gidx] = __float2half(inv1pexp(lam * f * 0.1f));
            } else {
                float2 pr = __half22float2(xl[gidx]);            // (x, lam)
                float uprev = __half2float(uin[gidx]);           // L1/L2-hot
                float tt = (uprev - pr.x) * 10.f + pr.y * f;     // (u-x)/tau+lam*v
                float uu = inv1pexp(tt * 0.1f);                  // sigmoid(-tt/eps)
                float res = 0.5f * (uprev + uu);                 // alpha = 0.5
                if constexpr (MODE == 2) ((float*)uout)[gidx] = res;
                else                     ((__half*)uout)[gidx] = __float2half(res);
            }
        }
    }
}

extern "C" void kernel_launch(void* const* d_in, const int* in_sizes, int n_in,
                              void* d_out, int out_size, void* d_ws, size_t ws_size,
                              hipStream_t stream) {
    const float* x = (const float*)d_in[0];
    const float* c = (const float*)d_in[1];

    __half* u0 = (__half*)d_ws;          // NPIX halfs = 12.6 MB
    __half* u1 = u0 + NPIX;              // 12.6 MB
    __half2* xl = (ws_size >= NPIX * 8)
        ? (__half2*)((char*)d_ws + NPIX * 4)
        : (__half2*)d_out;               // safe: per-pixel read-before-write

    dim3 grid(HW / TC, HW / TR, NIMG);   // 8 x 16 x 24 = 3072 blocks
    dim3 block(256);
    sig_step<0><<<grid, block, 0, stream>>>(x, c, nullptr, xl, u0);
    sig_step<1><<<grid, block, 0, stream>>>(x, c, u0, xl, u1);
    sig_step<1><<<grid, block, 0, stream>>>(x, c, u1, xl, u0);
    sig_step<1><<<grid, block, 0, stream>>>(x, c, u0, xl, u1);
    sig_step<1><<<grid, block, 0, stream>>>(x, c, u1, xl, u0);
    sig_step<2><<<grid, block, 0, stream>>>(x, c, u0, xl, d_out);
}